// Round 7
// baseline (178.359 us; speedup 1.0000x reference)
//
#include <hip/hip_runtime.h>

#define DIMB 2
#define DIMS 192
#define DPT 4          // d-outputs per thread
#define TX 16          // d-quads per block (64 d per block)
#define TY 16          // w rows per block
#define HCHUNK 6       // output h rows per block
#define ROWF 72        // floats per staged row (d0b-4 .. d0b+67)
#define PLANE_F 1296   // 18 rows * 72 floats per array
#define BUF_F 2816     // 11 segments * 256 floats (padded)
#define NSEG 11        // ceil(2*PLANE_F / 256)

// Async global->LDS staging (16B/lane, wave-uniform base — m104 contract).
#define GLOAD_LDS16(gp, lp) __builtin_amdgcn_global_load_lds( \
    (const __attribute__((address_space(1))) void*)(gp),      \
    (__attribute__((address_space(3))) void*)(lp), 16, 0, 0)

__device__ __forceinline__ float ncc_row3(const float (&Pm)[5][DPT],
                                          const float (&Pc)[5][DPT],
                                          const float (&Pn)[5][DPT])
{
    const float inv = 1.0f / 27.0f;
    float acc = 0.f;
#pragma unroll
    for (int j = 0; j < DPT; ++j) {
        const float sI  = Pm[0][j] + Pc[0][j] + Pn[0][j];
        const float sJ  = Pm[1][j] + Pc[1][j] + Pn[1][j];
        const float sII = Pm[2][j] + Pc[2][j] + Pn[2][j];
        const float sJJ = Pm[3][j] + Pc[3][j] + Pn[3][j];
        const float sIJ = Pm[4][j] + Pc[4][j] + Pn[4][j];
        const float uI = sI * inv;
        const float uJ = sJ * inv;
        const float cross = sIJ - uI * sJ;
        const float pvar  = sII - uI * sI;
        const float tvar  = sJJ - uJ * sJ;
        acc += (cross * cross) * __builtin_amdgcn_rcpf(tvar * pvar + 1e-5f);
    }
    return acc;
}

__global__ __launch_bounds__(256)
void FusedLocalNormalizedCrossCorrelationLoss_37838661877790_kernel(
    const float* __restrict__ pred, const float* __restrict__ targ,
    double* __restrict__ acc_out)
{
    __shared__ float L[2][BUF_F];    // double-buffered plane pair (22.5 KB)

    const int tx = threadIdx.x, ty = threadIdx.y;
    const int tid = ty * TX + tx;
    const int lane = tid & 63, wv = tid >> 6;
    const int d0b = blockIdx.x * (TX * DPT);     // 0, 64, 128
    const int w0  = blockIdx.y * TY;
    const int bz  = blockIdx.z;
    const int b   = bz >> 5;                     // 2 batches
    const int h0  = (bz & 31) * HCHUNK;          // 32 h-chunks

    // ---- per-thread stage-segment precompute (plane-invariant) ----
    int   sl[3]; int co[3]; const float* ab[3];
#pragma unroll
    for (int i = 0; i < 3; ++i) {
        const int s = wv + 4 * i;
        const int ss = (s < NSEG) ? s : 0;       // wave 3 has 2 segments
        const int fi = ss * 256 + lane * 4;
        const int a  = (fi >= PLANE_F) ? 1 : 0;
        int fi2 = fi - a * PLANE_F;
        if (fi2 > PLANE_F - 1) fi2 = PLANE_F - 1;   // LDS pad region
        const int r = fi2 / ROWF, c = fi2 % ROWF;
        int gd = d0b - 4 + c;                    // multiple of 4 -> 16B aligned
        gd = gd < 0 ? 0 : (gd > DIMS - 4 ? DIMS - 4 : gd);
        int wr = w0 - 1 + r;
        wr = wr < 0 ? 0 : (wr > DIMS - 1 ? DIMS - 1 : wr);
        sl[i] = ss * 256;                        // wave-uniform LDS float base
        co[i] = wr * DIMS + gd;                  // clamped; garbage masked later
        ab[i] = a ? targ : pred;
    }

    auto stage = [&](int buf, int hh) {
        const int hhc = hh < 0 ? 0 : (hh > DIMS - 1 ? DIMS - 1 : hh);
        const size_t po = ((size_t)b * DIMS + hhc) * (DIMS * DIMS);
#pragma unroll
        for (int i = 0; i < 3; ++i) {
            if (wv + 4 * i >= NSEG) break;       // wave-uniform
            GLOAD_LDS16(ab[i] + po + co[i], &L[buf][sl[i]]);
        }
    };

    // Global d-boundary zero masks (clamped staging puts garbage in halo).
    const bool lo_zero = (blockIdx.x == 0);
    const bool hi_zero = (blockIdx.x == gridDim.x - 1);
    const int rb0 = 4 * tx;

    // Conflict-free plane reader: one ds_read_b128 per row-array (provably
    // uniform 8 accesses/bank); d-window edges come from neighbor lanes via
    // shuffle (lane-1's .w = idx rb+3, lane+1's .x = idx rb+8). The R6 scalar
    // edge reads were 8-way bank-conflicted (all 64 lanes in one step-4
    // residue class -> 8 banks) = 1.4e7 conflict cycles.
    auto plane = [&](int buf, int hh, float (&P)[5][DPT]) {
#pragma unroll
        for (int c5 = 0; c5 < 5; ++c5)
#pragma unroll
            for (int j = 0; j < DPT; ++j) P[c5][j] = 0.f;
        if (hh < 0 || hh >= DIMS) return;        // uniform per block
        const float* Lp = &L[buf][0];
        const float* Lt = &L[buf][PLANE_F];
#pragma unroll
        for (int dw = 0; dw < 3; ++dw) {
            const int wr = w0 + ty + dw - 1;
            const int rb = (ty + dw) * ROWF + rb0;
            const float4 pm = *reinterpret_cast<const float4*>(Lp + rb + 4);
            const float4 tm = *reinterpret_cast<const float4*>(Lt + rb + 4);
            // block-halo edges: 4 active lanes per wave each (tiny, few banks)
            float p0e = 0.f, t0e = 0.f, p5e = 0.f, t5e = 0.f;
            if (tx == 0 && !lo_zero)      { p0e = Lp[rb + 3]; t0e = Lt[rb + 3]; }
            if (tx == TX - 1 && !hi_zero) { p5e = Lp[rb + 8]; t5e = Lt[rb + 8]; }
            // interior edges from neighbor lanes (all lanes execute shuffles)
            const float p0s = __shfl_up(pm.w, 1, 64);
            const float t0s = __shfl_up(tm.w, 1, 64);
            const float p5s = __shfl_down(pm.x, 1, 64);
            const float t5s = __shfl_down(tm.x, 1, 64);
            const float p0 = (tx == 0)      ? p0e : p0s;
            const float t0 = (tx == 0)      ? t0e : t0s;
            const float p5 = (tx == TX - 1) ? p5e : p5s;
            const float t5 = (tx == TX - 1) ? t5e : t5s;
            if (wr < 0 || wr >= DIMS) continue;  // garbage halo row (after shfl)

            const float pv[6] = {p0, pm.x, pm.y, pm.z, pm.w, p5};
            const float tv[6] = {t0, tm.x, tm.y, tm.z, tm.w, t5};
            float pp[6], tt[6], pt[6];
#pragma unroll
            for (int k = 0; k < 6; ++k) {
                pp[k] = pv[k] * pv[k];
                tt[k] = tv[k] * tv[k];
                pt[k] = pv[k] * tv[k];
            }
#pragma unroll
            for (int j = 0; j < DPT; ++j) {
                P[0][j] += pv[j] + pv[j+1] + pv[j+2];
                P[1][j] += tv[j] + tv[j+1] + tv[j+2];
                P[2][j] += pp[j] + pp[j+1] + pp[j+2];
                P[3][j] += tt[j] + tt[j+1] + tt[j+2];
                P[4][j] += pt[j] + pt[j+1] + pt[j+2];
            }
        }
    };

    // Plane q (hh = h0-1+q) lives in buffer q&1; 1 barrier per plane.
    float PA[5][DPT], PB[5][DPT], PC[5][DPT];
    float acc = 0.f;

    stage(0, h0 - 1);
    stage(1, h0);
    __syncthreads();                       // q0,q1 ready
    plane(0, h0 - 1, PA);
    __syncthreads();                       // all reads of buf0 done
    stage(0, h0 + 1);
    plane(1, h0, PB);
    __syncthreads();
    stage(1, h0 + 2);
    plane(0, h0 + 1, PC);  acc += ncc_row3(PA, PB, PC);
    __syncthreads();
    stage(0, h0 + 3);
    plane(1, h0 + 2, PA);  acc += ncc_row3(PB, PC, PA);
    __syncthreads();
    stage(1, h0 + 4);
    plane(0, h0 + 3, PB);  acc += ncc_row3(PC, PA, PB);
    __syncthreads();
    stage(0, h0 + 5);
    plane(1, h0 + 4, PC);  acc += ncc_row3(PA, PB, PC);
    __syncthreads();
    stage(1, h0 + 6);
    plane(0, h0 + 5, PA);  acc += ncc_row3(PB, PC, PA);
    __syncthreads();
    plane(1, h0 + 6, PB);  acc += ncc_row3(PC, PA, PB);

    // Reduction: wave shuffle tree -> LDS -> one fp64 atomic per block.
#pragma unroll
    for (int off = 32; off > 0; off >>= 1)
        acc += __shfl_down(acc, off, 64);
    __shared__ float wacc[4];
    if ((tid & 63) == 0) wacc[tid >> 6] = acc;
    __syncthreads();
    if (tid == 0) {
        const double s = (double)wacc[0] + (double)wacc[1]
                       + (double)wacc[2] + (double)wacc[3];
        atomicAdd(acc_out, s);
    }
}

__global__ void ncc_finalize(const double* __restrict__ acc,
                             float* __restrict__ out)
{
    const double n = (double)((size_t)DIMB * DIMS * DIMS * DIMS);
    out[0] = (float)(-acc[0] / n);
}

extern "C" void kernel_launch(void* const* d_in, const int* in_sizes, int n_in,
                              void* d_out, int out_size, void* d_ws, size_t ws_size,
                              hipStream_t stream) {
    const float* pred = (const float*)d_in[0];
    const float* targ = (const float*)d_in[1];
    double* acc = (double*)d_ws;

    hipMemsetAsync(d_ws, 0, sizeof(double), stream);

    dim3 block(TX, TY, 1);
    dim3 grid(DIMS / (TX * DPT), DIMS / TY, DIMB * (DIMS / HCHUNK)); // 3 x 12 x 64
    FusedLocalNormalizedCrossCorrelationLoss_37838661877790_kernel
        <<<grid, block, 0, stream>>>(pred, targ, acc);
    ncc_finalize<<<1, 1, 0, stream>>>(acc, (float*)d_out);
}